// Round 2
// baseline (390.781 us; speedup 1.0000x reference)
//
#include <hip/hip_runtime.h>

typedef __attribute__((ext_vector_type(8))) short bf16x8;
typedef __attribute__((ext_vector_type(16))) float f32x16;
typedef __attribute__((ext_vector_type(4))) float f32x4;
typedef __attribute__((ext_vector_type(4))) unsigned u32x4;

#define LN_EPS 1e-5f

__device__ __forceinline__ unsigned short f2bf(float f) {
    unsigned u = __float_as_uint(f);
    unsigned r = (u + 0x7FFFu + ((u >> 16) & 1u)) >> 16;
    return (unsigned short)r;
}

__device__ __forceinline__ unsigned cvt_pk_bf16(float lo, float hi) {
    unsigned r;
    asm("v_cvt_pk_bf16_f32 %0, %1, %2" : "=v"(r) : "v"(lo), "v"(hi));
    return r;
}

// v_permlane32_swap_b32 a, b:  a' = {a.lo32lanes, b.lo32lanes},
//                              b' = {a.hi32lanes, b.hi32lanes}
__device__ __forceinline__ void permswap(unsigned& a, unsigned& b) {
    asm("v_permlane32_swap_b32 %0, %1" : "+v"(a), "+v"(b));
}

// ---------------------------------------------------------------------------
// prep: build bf16 weight images in workspace.
//   wt_lin [128][256]            = W_lin^T  (B-operand image for atoms_gemm)
//   wimg   [5][4][8][64][8] bf16 = {W1a,W1b,W1c,W2,W3}^T in MFMA A-frag order:
//     element (mat,f,ks,lane,j) = W^T[32f + (lane&31)][16ks + 8*(lane>>5) + j]
//   -> hot-loop A-frag load is one fully coalesced 1KB global_load_dwordx4.
// ---------------------------------------------------------------------------
__global__ void prep_weights(const float* __restrict__ W_lin,
                             const float* __restrict__ W1,
                             const float* __restrict__ W2,
                             const float* __restrict__ W3,
                             unsigned short* __restrict__ wt_lin,
                             unsigned short* __restrict__ wimg) {
    int i = blockIdx.x * blockDim.x + threadIdx.x;
    if (i < 128 * 256) {
        int n = i >> 8, k = i & 255;
        wt_lin[n * 256 + k] = f2bf(W_lin[k * 128 + n]);
    } else if (i < 128 * 256 + 5 * 16384) {
        int j = i - 128 * 256;
        int mat = j >> 14, r = j & 16383;
        int jj = r & 7, l = (r >> 3) & 63, ks = (r >> 9) & 7, f = r >> 12;
        int n = 32 * f + (l & 31);
        int k = 16 * ks + 8 * (l >> 5) + jj;
        float v;
        if (mat < 3)       v = W1[(mat * 128 + k) * 128 + n];
        else if (mat == 3) v = W2[k * 128 + n];
        else               v = W3[k * 128 + n];
        wimg[j + mat * 0 + (j - r) * 0 + (mat * 16384 + r) - j] = f2bf(v);  // = wimg[mat*16384 + r]
    }
}

// ---------------------------------------------------------------------------
// atoms_gemm: atom_scalars(bf16)[N][128] = atom_features[N][256] @ W_lin
// 256 thr / 4 waves, 128 rows per block, mfma 32x32x16, no LDS.
// ---------------------------------------------------------------------------
__global__ void atoms_gemm(const float* __restrict__ af,
                           const unsigned short* __restrict__ wt_lin,
                           unsigned short* __restrict__ atoms_bf,
                           int Natoms) {
    const int wv = threadIdx.x >> 6, lane = threadIdx.x & 63;
    const int l31 = lane & 31, g8 = (lane >> 5) * 8, g4 = (lane >> 5) * 4;
    const int R = blockIdx.x * 128 + wv * 32;

    f32x16 acc[4];
#pragma unroll
    for (int f = 0; f < 4; ++f)
#pragma unroll
        for (int e = 0; e < 16; ++e) acc[f][e] = 0.0f;

    int arow = R + l31;
    if (arow >= Natoms) arow = Natoms - 1;
    const float* ap = af + (size_t)arow * 256;

#pragma unroll
    for (int ks = 0; ks < 16; ++ks) {
        const int k0 = ks * 16 + g8;
        float4 x0 = *(const float4*)(ap + k0);
        float4 x1 = *(const float4*)(ap + k0 + 4);
        bf16x8 a;
        a[0] = (short)f2bf(x0.x); a[1] = (short)f2bf(x0.y);
        a[2] = (short)f2bf(x0.z); a[3] = (short)f2bf(x0.w);
        a[4] = (short)f2bf(x1.x); a[5] = (short)f2bf(x1.y);
        a[6] = (short)f2bf(x1.z); a[7] = (short)f2bf(x1.w);
#pragma unroll
        for (int f = 0; f < 4; ++f) {
            bf16x8 b = *(const bf16x8*)(wt_lin + (32 * f + l31) * 256 + k0);
            acc[f] = __builtin_amdgcn_mfma_f32_32x32x16_bf16(a, b, acc[f], 0, 0, 0);
        }
    }

#pragma unroll
    for (int f = 0; f < 4; ++f) {
        const int col = 32 * f + l31;
#pragma unroll
        for (int r = 0; r < 16; ++r) {
            int row = R + (r & 3) + 8 * (r >> 2) + g4;
            if (row < Natoms) atoms_bf[(size_t)row * 128 + col] = f2bf(acc[f][r]);
        }
    }
}

// ---------------------------------------------------------------------------
// edge_fused: gather -> 3-layer MLP -> residual -> LayerNorm, all transposed
// (lane = edge at every layer), zero LDS, zero barriers.
// 256 thr / 4 waves, 32 edges per wave, 128 per block.
// A-operand  = weight frags streamed from the packed global image (L1/L2-hot).
// B-operand  = layer input: gathered atom rows / ef (layer 1), or in-register
//              repack of the previous accumulator via cvt_pk + permlane32_swap.
// ---------------------------------------------------------------------------
__global__ __launch_bounds__(256, 3) void edge_fused(
    const float* __restrict__ ef, const int* __restrict__ eidx,
    const unsigned short* __restrict__ atoms_bf,
    const unsigned short* __restrict__ wimg,
    const float* __restrict__ b1, const float* __restrict__ b2,
    const float* __restrict__ b3, const float* __restrict__ gamma_,
    const float* __restrict__ beta_, float* __restrict__ out, int E) {
    const int lane = threadIdx.x & 63;
    const int wv = threadIdx.x >> 6;
    const int l31 = lane & 31;
    const int hi = lane >> 5;
    const int h8 = hi * 8;

    const int e0 = blockIdx.x * 128 + wv * 32 + l31;
    const int e = e0 < E ? e0 : E - 1;
    const int dstI = eidx[e];
    const int srcI = eidx[E + e];
    const unsigned short* dstRow = atoms_bf + (size_t)dstI * 128;
    const unsigned short* srcRow = atoms_bf + (size_t)srcI * 128;
    const float* efRow = ef + (size_t)e * 128;

    const unsigned short* wbase = wimg + lane * 8;

    f32x16 acc[4];

    // acc init = bias broadcast: acc[f][r] = bias[32f + (r&3) + 8(r>>2) + 4hi]
    auto initb = [&](const float* __restrict__ bb) {
#pragma unroll
        for (int f = 0; f < 4; ++f)
#pragma unroll
            for (int m = 0; m < 4; ++m) {
                f32x4 b4 = *(const f32x4*)(bb + 32 * f + 8 * m + 4 * hi);
#pragma unroll
                for (int i = 0; i < 4; ++i) acc[f][4 * m + i] = b4[i];
            }
    };

    bf16x8 frag[8];
    // Repack C-layout acc (lane=edge col; rows=(r&3)+8(r>>2)+4hi) into
    // B-frags (k contiguous per lane) for the next layer, fusing relu.
    // frag[2f+k1] = { swap(pk0[2k1],pk0[2k1+1]).a, swap(pk1[2k1],pk1[2k1+1]).a,
    //                 swap(...).b, swap(...).b }
    auto build_frags = [&]() {
#pragma unroll
        for (int f = 0; f < 4; ++f) {
            unsigned pk0[4], pk1[4];
#pragma unroll
            for (int m = 0; m < 4; ++m) {
                float a0 = fmaxf(acc[f][4 * m + 0], 0.0f);
                float a1 = fmaxf(acc[f][4 * m + 1], 0.0f);
                float a2 = fmaxf(acc[f][4 * m + 2], 0.0f);
                float a3 = fmaxf(acc[f][4 * m + 3], 0.0f);
                pk0[m] = cvt_pk_bf16(a0, a1);
                pk1[m] = cvt_pk_bf16(a2, a3);
            }
#pragma unroll
            for (int k1 = 0; k1 < 2; ++k1) {
                unsigned x0 = pk0[2 * k1], y0 = pk0[2 * k1 + 1];
                unsigned x1 = pk1[2 * k1], y1 = pk1[2 * k1 + 1];
                permswap(x0, y0);
                permswap(x1, y1);
                union { u32x4 u; bf16x8 b; } cv;
                cv.u = (u32x4){x0, x1, y0, y1};
                frag[2 * f + k1] = cv.b;
            }
        }
    };

    // ---------------- layer 1: acc = W1^T @ [dst|src|ef]^T + b1 ----------
    initb(b1);
#pragma unroll
    for (int ks = 0; ks < 8; ++ks) {
        bf16x8 bx = *(const bf16x8*)(dstRow + ks * 16 + h8);
#pragma unroll
        for (int f = 0; f < 4; ++f) {
            bf16x8 a = *(const bf16x8*)(wbase + ((0 * 4 + f) * 8 + ks) * 512);
            acc[f] = __builtin_amdgcn_mfma_f32_32x32x16_bf16(a, bx, acc[f], 0, 0, 0);
        }
    }
#pragma unroll
    for (int ks = 0; ks < 8; ++ks) {
        bf16x8 bx = *(const bf16x8*)(srcRow + ks * 16 + h8);
#pragma unroll
        for (int f = 0; f < 4; ++f) {
            bf16x8 a = *(const bf16x8*)(wbase + ((1 * 4 + f) * 8 + ks) * 512);
            acc[f] = __builtin_amdgcn_mfma_f32_32x32x16_bf16(a, bx, acc[f], 0, 0, 0);
        }
    }
#pragma unroll
    for (int ks = 0; ks < 8; ++ks) {
        f32x4 x0 = *(const f32x4*)(efRow + ks * 16 + h8);
        f32x4 x1 = *(const f32x4*)(efRow + ks * 16 + h8 + 4);
        union { u32x4 u; bf16x8 b; } cv;
        cv.u = (u32x4){cvt_pk_bf16(x0[0], x0[1]), cvt_pk_bf16(x0[2], x0[3]),
                       cvt_pk_bf16(x1[0], x1[1]), cvt_pk_bf16(x1[2], x1[3])};
#pragma unroll
        for (int f = 0; f < 4; ++f) {
            bf16x8 a = *(const bf16x8*)(wbase + ((2 * 4 + f) * 8 + ks) * 512);
            acc[f] = __builtin_amdgcn_mfma_f32_32x32x16_bf16(a, cv.b, acc[f], 0, 0, 0);
        }
    }

    // ---------------- layer 2 ----------------
    build_frags();
    initb(b2);
#pragma unroll
    for (int ks = 0; ks < 8; ++ks)
#pragma unroll
        for (int f = 0; f < 4; ++f) {
            bf16x8 a = *(const bf16x8*)(wbase + ((3 * 4 + f) * 8 + ks) * 512);
            acc[f] = __builtin_amdgcn_mfma_f32_32x32x16_bf16(a, frag[ks], acc[f], 0, 0, 0);
        }

    // ---------------- layer 3 ----------------
    build_frags();
    initb(b3);
#pragma unroll
    for (int ks = 0; ks < 8; ++ks)
#pragma unroll
        for (int f = 0; f < 4; ++f) {
            bf16x8 a = *(const bf16x8*)(wbase + ((4 * 4 + f) * 8 + ks) * 512);
            acc[f] = __builtin_amdgcn_mfma_f32_32x32x16_bf16(a, frag[ks], acc[f], 0, 0, 0);
        }

    // ---------------- residual + LayerNorm + store ----------------
    float s = 0.0f, q = 0.0f;
#pragma unroll
    for (int f = 0; f < 4; ++f)
#pragma unroll
        for (int m = 0; m < 4; ++m) {
            f32x4 r4 = *(const f32x4*)(efRow + 32 * f + 8 * m + 4 * hi);
#pragma unroll
            for (int i = 0; i < 4; ++i) {
                float v = acc[f][4 * m + i] + r4[i];
                acc[f][4 * m + i] = v;
                s += v;
                q += v * v;
            }
        }
    s += __shfl_xor(s, 32, 64);
    q += __shfl_xor(q, 32, 64);
    const float mu = s * (1.0f / 128.0f);
    const float var = q * (1.0f / 128.0f) - mu * mu;
    const float rs = rsqrtf(var + LN_EPS);

    if (e0 < E) {
#pragma unroll
        for (int f = 0; f < 4; ++f)
#pragma unroll
            for (int m = 0; m < 4; ++m) {
                f32x4 g4 = *(const f32x4*)(gamma_ + 32 * f + 8 * m + 4 * hi);
                f32x4 be4 = *(const f32x4*)(beta_ + 32 * f + 8 * m + 4 * hi);
                f32x4 o;
#pragma unroll
                for (int i = 0; i < 4; ++i)
                    o[i] = (acc[f][4 * m + i] - mu) * rs * g4[i] + be4[i];
                *(f32x4*)(out + (size_t)e * 128 + 32 * f + 8 * m + 4 * hi) = o;
            }
    }
}

// ---------------------------------------------------------------------------
extern "C" void kernel_launch(void* const* d_in, const int* in_sizes, int n_in,
                              void* d_out, int out_size, void* d_ws, size_t ws_size,
                              hipStream_t stream) {
    const float* atom_features = (const float*)d_in[0];
    const float* edge_features = (const float*)d_in[1];
    const int* edge_index = (const int*)d_in[2];
    const float* W_lin = (const float*)d_in[3];
    const float* W1 = (const float*)d_in[4];
    const float* b1 = (const float*)d_in[5];
    const float* W2 = (const float*)d_in[6];
    const float* b2 = (const float*)d_in[7];
    const float* W3 = (const float*)d_in[8];
    const float* b3 = (const float*)d_in[9];
    const float* gamma_ = (const float*)d_in[10];
    const float* beta_ = (const float*)d_in[11];
    float* out = (float*)d_out;

    const int Natoms = in_sizes[0] / 256;
    const int E = in_sizes[1] / 128;

    unsigned short* atoms_bf = (unsigned short*)d_ws;
    unsigned short* wt_lin = atoms_bf + (size_t)Natoms * 128;
    unsigned short* wimg = wt_lin + 128 * 256;

    const int prep_items = 128 * 256 + 5 * 16384;
    prep_weights<<<(prep_items + 255) / 256, 256, 0, stream>>>(W_lin, W1, W2, W3,
                                                               wt_lin, wimg);
    atoms_gemm<<<(Natoms + 127) / 128, 256, 0, stream>>>(atom_features, wt_lin,
                                                         atoms_bf, Natoms);
    edge_fused<<<(E + 127) / 128, 256, 0, stream>>>(edge_features, edge_index,
                                                    atoms_bf, wimg, b1, b2, b3,
                                                    gamma_, beta_, out, E);
}

// Round 3
// 266.780 us; speedup vs baseline: 1.4648x; 1.4648x over previous
//
#include <hip/hip_runtime.h>

typedef __attribute__((ext_vector_type(8))) short bf16x8;
typedef __attribute__((ext_vector_type(16))) float f32x16;
typedef __attribute__((ext_vector_type(4))) float f32x4;
typedef __attribute__((ext_vector_type(4))) unsigned u32x4;

#define LN_EPS 1e-5f

__device__ __forceinline__ unsigned short f2bf(float f) {
    unsigned u = __float_as_uint(f);
    unsigned r = (u + 0x7FFFu + ((u >> 16) & 1u)) >> 16;
    return (unsigned short)r;
}

__device__ __forceinline__ unsigned cvt_pk_bf16(float lo, float hi) {
    unsigned r;
    asm("v_cvt_pk_bf16_f32 %0, %1, %2" : "=v"(r) : "v"(lo), "v"(hi));
    return r;
}

__device__ __forceinline__ void permswap(unsigned& a, unsigned& b) {
    asm("v_permlane32_swap_b32 %0, %1" : "+v"(a), "+v"(b));
}

// ---------------------------------------------------------------------------
// prep: build bf16 weight images in workspace.
//   wt_lin [128][256]            = W_lin^T  (B-operand image for atoms_gemm)
//   wimg   [5][4][8][64][8] bf16 = {W1a,W1b,W1c,W2,W3}^T in MFMA A-frag order:
//     element (mat,f,ks,lane,j) = W^T[32f + (lane&31)][16ks + 8*(lane>>5) + j]
//   mats 0..3 (W1a,W1b,W1c,W2) are staged to LDS by edge_fused; mat 4 (W3)
//   is read from global (32 KB, L1-resident).
// ---------------------------------------------------------------------------
__global__ void prep_weights(const float* __restrict__ W_lin,
                             const float* __restrict__ W1,
                             const float* __restrict__ W2,
                             const float* __restrict__ W3,
                             unsigned short* __restrict__ wt_lin,
                             unsigned short* __restrict__ wimg) {
    int i = blockIdx.x * blockDim.x + threadIdx.x;
    if (i < 128 * 256) {
        int n = i >> 8, k = i & 255;
        wt_lin[n * 256 + k] = f2bf(W_lin[k * 128 + n]);
    } else if (i < 128 * 256 + 5 * 16384) {
        int j = i - 128 * 256;
        int mat = j >> 14, r = j & 16383;
        int jj = r & 7, l = (r >> 3) & 63, ks = (r >> 9) & 7, f = r >> 12;
        int n = 32 * f + (l & 31);
        int k = 16 * ks + 8 * (l >> 5) + jj;
        float v;
        if (mat < 3)       v = W1[(mat * 128 + k) * 128 + n];
        else if (mat == 3) v = W2[k * 128 + n];
        else               v = W3[k * 128 + n];
        wimg[j] = f2bf(v);
    }
}

// ---------------------------------------------------------------------------
// atoms_gemm: atom_scalars(bf16)[N][128] = atom_features[N][256] @ W_lin
// ---------------------------------------------------------------------------
__global__ void atoms_gemm(const float* __restrict__ af,
                           const unsigned short* __restrict__ wt_lin,
                           unsigned short* __restrict__ atoms_bf,
                           int Natoms) {
    const int wv = threadIdx.x >> 6, lane = threadIdx.x & 63;
    const int l31 = lane & 31, g8 = (lane >> 5) * 8, g4 = (lane >> 5) * 4;
    const int R = blockIdx.x * 128 + wv * 32;

    f32x16 acc[4];
#pragma unroll
    for (int f = 0; f < 4; ++f)
#pragma unroll
        for (int e = 0; e < 16; ++e) acc[f][e] = 0.0f;

    int arow = R + l31;
    if (arow >= Natoms) arow = Natoms - 1;
    const float* ap = af + (size_t)arow * 256;

#pragma unroll
    for (int ks = 0; ks < 16; ++ks) {
        const int k0 = ks * 16 + g8;
        float4 x0 = *(const float4*)(ap + k0);
        float4 x1 = *(const float4*)(ap + k0 + 4);
        bf16x8 a;
        a[0] = (short)f2bf(x0.x); a[1] = (short)f2bf(x0.y);
        a[2] = (short)f2bf(x0.z); a[3] = (short)f2bf(x0.w);
        a[4] = (short)f2bf(x1.x); a[5] = (short)f2bf(x1.y);
        a[6] = (short)f2bf(x1.z); a[7] = (short)f2bf(x1.w);
#pragma unroll
        for (int f = 0; f < 4; ++f) {
            bf16x8 b = *(const bf16x8*)(wt_lin + (32 * f + l31) * 256 + k0);
            acc[f] = __builtin_amdgcn_mfma_f32_32x32x16_bf16(a, b, acc[f], 0, 0, 0);
        }
    }

#pragma unroll
    for (int f = 0; f < 4; ++f) {
        const int col = 32 * f + l31;
#pragma unroll
        for (int r = 0; r < 16; ++r) {
            int row = R + (r & 3) + 8 * (r >> 2) + g4;
            if (row < Natoms) atoms_bf[(size_t)row * 128 + col] = f2bf(acc[f][r]);
        }
    }
}

// ---------------------------------------------------------------------------
// edge_fused: gather -> 3-layer MLP -> residual -> LayerNorm, transposed
// (lane = edge), 512 thr / 8 waves, 64 edges per wave (2 subtiles A,B).
// W1+W2 (128 KB) staged once to LDS (one barrier); W3 from global (L1-hot).
// Inter-layer repack in-register via cvt_pk + permlane32_swap. No other LDS.
// ---------------------------------------------------------------------------
__global__ __launch_bounds__(512, 2) void edge_fused(
    const float* __restrict__ ef, const int* __restrict__ eidx,
    const unsigned short* __restrict__ atoms_bf,
    const unsigned short* __restrict__ wimg,
    const float* __restrict__ b1, const float* __restrict__ b2,
    const float* __restrict__ b3, const float* __restrict__ gamma_,
    const float* __restrict__ beta_, float* __restrict__ out, int E) {
    __shared__ unsigned short wlds[4 * 16384];  // 128 KB: W1a,W1b,W1c,W2

    const int tid = threadIdx.x;
    const int lane = tid & 63, wv = tid >> 6;
    const int l31 = lane & 31, hi = lane >> 5, h8 = hi * 8;

    // ---- stage W1+W2 frag image: 512 thr x 16 B x 16 iters (linear) ----
    {
        const char* s = (const char*)wimg;
        char* d = (char*)wlds;
        const int o = tid * 16;
#pragma unroll
        for (int i = 0; i < 16; ++i)
            __builtin_amdgcn_global_load_lds(
                (const __attribute__((address_space(1))) unsigned int*)(s + o + i * 8192),
                (__attribute__((address_space(3))) unsigned int*)(d + o + i * 8192),
                16, 0, 0);
    }

    const int e0a = blockIdx.x * 512 + wv * 64 + l31;
    const int e0b = e0a + 32;
    const int ea = e0a < E ? e0a : E - 1;
    const int eb = e0b < E ? e0b : E - 1;
    const int dA = eidx[ea], sA = eidx[E + ea];
    const int dB = eidx[eb], sB = eidx[E + eb];
    const unsigned short* dRowA = atoms_bf + (size_t)dA * 128;
    const unsigned short* sRowA = atoms_bf + (size_t)sA * 128;
    const unsigned short* dRowB = atoms_bf + (size_t)dB * 128;
    const unsigned short* sRowB = atoms_bf + (size_t)sB * 128;
    const float* efA = ef + (size_t)ea * 128;
    const float* efB = ef + (size_t)eb * 128;

    // ---- preload dst gathers into regs: overlaps the staging wait ----
    bf16x8 gdA[8], gdB[8];
#pragma unroll
    for (int ks = 0; ks < 8; ++ks) {
        gdA[ks] = *(const bf16x8*)(dRowA + ks * 16 + h8);
        gdB[ks] = *(const bf16x8*)(dRowB + ks * 16 + h8);
    }

    f32x16 accA[4], accB[4];
    auto initb = [&](const float* __restrict__ bb) {
#pragma unroll
        for (int f = 0; f < 4; ++f)
#pragma unroll
            for (int m = 0; m < 4; ++m) {
                f32x4 b4 = *(const f32x4*)(bb + 32 * f + 8 * m + 4 * hi);
#pragma unroll
                for (int i = 0; i < 4; ++i) {
                    accA[f][4 * m + i] = b4[i];
                    accB[f][4 * m + i] = b4[i];
                }
            }
    };

    // Repack C-layout acc (lane=edge col; rows=(r&3)+8(r>>2)+4hi) into
    // B-frags (k contiguous per lane) for the next layer, fusing relu.
    auto build_frags = [&](f32x16* acc, bf16x8* frag) {
#pragma unroll
        for (int f = 0; f < 4; ++f) {
            unsigned pk0[4], pk1[4];
#pragma unroll
            for (int m = 0; m < 4; ++m) {
                float a0 = fmaxf(acc[f][4 * m + 0], 0.0f);
                float a1 = fmaxf(acc[f][4 * m + 1], 0.0f);
                float a2 = fmaxf(acc[f][4 * m + 2], 0.0f);
                float a3 = fmaxf(acc[f][4 * m + 3], 0.0f);
                pk0[m] = cvt_pk_bf16(a0, a1);
                pk1[m] = cvt_pk_bf16(a2, a3);
            }
#pragma unroll
            for (int k1 = 0; k1 < 2; ++k1) {
                unsigned x0 = pk0[2 * k1], y0 = pk0[2 * k1 + 1];
                unsigned x1 = pk1[2 * k1], y1 = pk1[2 * k1 + 1];
                permswap(x0, y0);
                permswap(x1, y1);
                union { u32x4 u; bf16x8 b; } cv;
                cv.u = (u32x4){x0, x1, y0, y1};
                frag[2 * f + k1] = cv.b;
            }
        }
    };

    const unsigned short* lbase = wlds + lane * 8;  // + ((mat*4+f)*8+ks)*512

    __syncthreads();

    // ---------------- layer 1: acc = W1^T @ [dst|src|ef]^T + b1 ----------
    initb(b1);
#pragma unroll
    for (int ks = 0; ks < 8; ++ks) {
#pragma unroll
        for (int f = 0; f < 4; ++f) {
            bf16x8 a = *(const bf16x8*)(lbase + ((0 * 4 + f) * 8 + ks) * 512);
            accA[f] = __builtin_amdgcn_mfma_f32_32x32x16_bf16(a, gdA[ks], accA[f], 0, 0, 0);
            accB[f] = __builtin_amdgcn_mfma_f32_32x32x16_bf16(a, gdB[ks], accB[f], 0, 0, 0);
        }
    }
#pragma unroll
    for (int ks = 0; ks < 8; ++ks) {
        bf16x8 bA = *(const bf16x8*)(sRowA + ks * 16 + h8);
        bf16x8 bB = *(const bf16x8*)(sRowB + ks * 16 + h8);
#pragma unroll
        for (int f = 0; f < 4; ++f) {
            bf16x8 a = *(const bf16x8*)(lbase + ((1 * 4 + f) * 8 + ks) * 512);
            accA[f] = __builtin_amdgcn_mfma_f32_32x32x16_bf16(a, bA, accA[f], 0, 0, 0);
            accB[f] = __builtin_amdgcn_mfma_f32_32x32x16_bf16(a, bB, accB[f], 0, 0, 0);
        }
    }
#pragma unroll
    for (int ks = 0; ks < 8; ++ks) {
        f32x4 xa0 = *(const f32x4*)(efA + ks * 16 + h8);
        f32x4 xa1 = *(const f32x4*)(efA + ks * 16 + h8 + 4);
        f32x4 xb0 = *(const f32x4*)(efB + ks * 16 + h8);
        f32x4 xb1 = *(const f32x4*)(efB + ks * 16 + h8 + 4);
        union { u32x4 u; bf16x8 b; } ca, cb;
        ca.u = (u32x4){cvt_pk_bf16(xa0[0], xa0[1]), cvt_pk_bf16(xa0[2], xa0[3]),
                       cvt_pk_bf16(xa1[0], xa1[1]), cvt_pk_bf16(xa1[2], xa1[3])};
        cb.u = (u32x4){cvt_pk_bf16(xb0[0], xb0[1]), cvt_pk_bf16(xb0[2], xb0[3]),
                       cvt_pk_bf16(xb1[0], xb1[1]), cvt_pk_bf16(xb1[2], xb1[3])};
#pragma unroll
        for (int f = 0; f < 4; ++f) {
            bf16x8 a = *(const bf16x8*)(lbase + ((2 * 4 + f) * 8 + ks) * 512);
            accA[f] = __builtin_amdgcn_mfma_f32_32x32x16_bf16(a, ca.b, accA[f], 0, 0, 0);
            accB[f] = __builtin_amdgcn_mfma_f32_32x32x16_bf16(a, cb.b, accB[f], 0, 0, 0);
        }
    }

    // ---------------- layer 2 (W2 in LDS, mat 3) ----------------
    bf16x8 frA[8], frB[8];
    build_frags(accA, frA);
    build_frags(accB, frB);
    initb(b2);
#pragma unroll
    for (int ks = 0; ks < 8; ++ks)
#pragma unroll
        for (int f = 0; f < 4; ++f) {
            bf16x8 a = *(const bf16x8*)(lbase + ((3 * 4 + f) * 8 + ks) * 512);
            accA[f] = __builtin_amdgcn_mfma_f32_32x32x16_bf16(a, frA[ks], accA[f], 0, 0, 0);
            accB[f] = __builtin_amdgcn_mfma_f32_32x32x16_bf16(a, frB[ks], accB[f], 0, 0, 0);
        }

    // ---------------- layer 3 (W3 from global, L1-hot 32 KB) ----------------
    build_frags(accA, frA);
    build_frags(accB, frB);
    initb(b3);
    const unsigned short* wg3 = wimg + 4 * 16384 + lane * 8;
#pragma unroll
    for (int ks = 0; ks < 8; ++ks)
#pragma unroll
        for (int f = 0; f < 4; ++f) {
            bf16x8 a = *(const bf16x8*)(wg3 + (f * 8 + ks) * 512);
            accA[f] = __builtin_amdgcn_mfma_f32_32x32x16_bf16(a, frA[ks], accA[f], 0, 0, 0);
            accB[f] = __builtin_amdgcn_mfma_f32_32x32x16_bf16(a, frB[ks], accB[f], 0, 0, 0);
        }

    // ---------------- residual + LayerNorm + store (per subtile) ----------
    auto epilogue = [&](f32x16* acc, const float* efRow, int e0) {
        float s = 0.0f, q = 0.0f;
#pragma unroll
        for (int f = 0; f < 4; ++f)
#pragma unroll
            for (int m = 0; m < 4; ++m) {
                f32x4 r4 = *(const f32x4*)(efRow + 32 * f + 8 * m + 4 * hi);
#pragma unroll
                for (int i = 0; i < 4; ++i) {
                    float v = acc[f][4 * m + i] + r4[i];
                    acc[f][4 * m + i] = v;
                    s += v;
                    q += v * v;
                }
            }
        s += __shfl_xor(s, 32, 64);
        q += __shfl_xor(q, 32, 64);
        const float mu = s * (1.0f / 128.0f);
        const float var = q * (1.0f / 128.0f) - mu * mu;
        const float rs = rsqrtf(var + LN_EPS);
        if (e0 < E) {
            float* orow = out + (size_t)e0 * 128;
#pragma unroll
            for (int f = 0; f < 4; ++f)
#pragma unroll
                for (int m = 0; m < 4; ++m) {
                    f32x4 g4 = *(const f32x4*)(gamma_ + 32 * f + 8 * m + 4 * hi);
                    f32x4 be4 = *(const f32x4*)(beta_ + 32 * f + 8 * m + 4 * hi);
                    f32x4 o;
#pragma unroll
                    for (int i = 0; i < 4; ++i)
                        o[i] = (acc[f][4 * m + i] - mu) * rs * g4[i] + be4[i];
                    *(f32x4*)(orow + 32 * f + 8 * m + 4 * hi) = o;
                }
        }
    };
    epilogue(accA, efA, e0a);
    epilogue(accB, efB, e0b);
}

// ---------------------------------------------------------------------------
extern "C" void kernel_launch(void* const* d_in, const int* in_sizes, int n_in,
                              void* d_out, int out_size, void* d_ws, size_t ws_size,
                              hipStream_t stream) {
    const float* atom_features = (const float*)d_in[0];
    const float* edge_features = (const float*)d_in[1];
    const int* edge_index = (const int*)d_in[2];
    const float* W_lin = (const float*)d_in[3];
    const float* W1 = (const float*)d_in[4];
    const float* b1 = (const float*)d_in[5];
    const float* W2 = (const float*)d_in[6];
    const float* b2 = (const float*)d_in[7];
    const float* W3 = (const float*)d_in[8];
    const float* b3 = (const float*)d_in[9];
    const float* gamma_ = (const float*)d_in[10];
    const float* beta_ = (const float*)d_in[11];
    float* out = (float*)d_out;

    const int Natoms = in_sizes[0] / 256;
    const int E = in_sizes[1] / 128;

    unsigned short* atoms_bf = (unsigned short*)d_ws;
    unsigned short* wt_lin = atoms_bf + (size_t)Natoms * 128;
    unsigned short* wimg = wt_lin + 128 * 256;

    const int prep_items = 128 * 256 + 5 * 16384;
    prep_weights<<<(prep_items + 255) / 256, 256, 0, stream>>>(W_lin, W1, W2, W3,
                                                               wt_lin, wimg);
    atoms_gemm<<<(Natoms + 127) / 128, 256, 0, stream>>>(atom_features, wt_lin,
                                                         atoms_bf, Natoms);
    edge_fused<<<(E + 511) / 512, 512, 0, stream>>>(edge_features, edge_index,
                                                    atoms_bf, wimg, b1, b2, b3,
                                                    gamma_, beta_, out, E);
}